// Round 13
// baseline (841.667 us; speedup 1.0000x reference)
//
#include <hip/hip_runtime.h>

// MaxUnpooling2D scatter-add, fully deterministic two-phase (NO global atomics).
// updates [8,256,256,64] f32, mask int32 (flat index into [512*512*64] plane).
// out [8,512,512,64] f32, duplicates sum.
//
// dest flat (within batch plane) = (m & ~63) | c, c = element's own channel.
// bucket (global) = batch*2048 + (m>>13): 128 output pixels = 32 KB region.
// local idx in bucket = (m & 0x1FC0) | c, 13 bits.
//
// Phase A (bin16k): per 16384-elem tile, sort records by bucket in LDS,
//   write them as ONE dense contiguous 128 KB block + u16 prefix table.
// Phase B (bucket_gather): 256 threads/WG, ONE RUN PER THREAD (256 tiles per
//   batch = 256 runs per bucket): thread t reads its run bounds directly,
//   then drains ~8 independent records (no rank walk, no prefix scan, no
//   dependent addressing) into LDS atomics; dense 32 KB cached write.
//   (r10-r12 post-mortem: per-lane dependent chains pinned gather at ~300us
//   across three inner-loop variants; this removes the chain entirely.)

static constexpr int PER_B  = 1 << 22;             // 4,194,304 elems/batch
static constexpr int NB     = 8;
static constexpr int N_ELEM = NB * PER_B;          // 33,554,432
static constexpr int BPB    = 2048;                // buckets per batch
static constexpr int NBUCK  = NB * BPB;            // 16384
static constexpr int TILE   = 16384;               // elements per bin WG
static constexpr int NTILE  = N_ELEM / TILE;       // 2048
static constexpr int TPB    = PER_B / TILE;        // 256 tiles (runs) per batch
static constexpr int EPT    = TILE / 4 / 1024;     // 4 vec4 loads per thread
static constexpr int BSA    = 1024;                // bin threads (16 waves)
static constexpr int BSG    = 256;                 // gather threads (4 waves)
static constexpr size_t PFX_BYTES  = (size_t)NTILE * BPB * 2;  // 8 MB
static constexpr size_t REC_BYTES  = (size_t)N_ELEM * 8;       // 268.4 MB exact
static constexpr size_t SREC_BYTES = (size_t)TILE * 8;         // 128 KB dynamic LDS

typedef int      i4v __attribute__((ext_vector_type(4)));
typedef float    f4v __attribute__((ext_vector_type(4)));
typedef unsigned u2v __attribute__((ext_vector_type(2)));

// ---- Phase A: LDS multisplit -> dense per-tile record block + prefix table
// 1024 threads, 16 elems/thread, 16 KB static + 128 KB dynamic -> 1 WG/CU.
__global__ __launch_bounds__(BSA)
void bin16k(const float* __restrict__ upd,
            const int*  __restrict__ mask,
            unsigned*   __restrict__ pfx_tab32,   // u16 pairs, written as u32
            u2v*        __restrict__ rec) {
    __shared__ unsigned cnt[BPB];      // 8 KB
    __shared__ unsigned pfx[BPB];      // 8 KB exclusive prefix
    __shared__ unsigned wsum[16];      // wave partial sums
    extern __shared__ u2v srec[];      // 128 KB locally-sorted records

    const int t = threadIdx.x;
    const int tile  = blockIdx.x;
    const int tile0 = tile * TILE;                  // tile fully inside one batch

    cnt[t] = 0; cnt[t + 1024] = 0;
    __syncthreads();

    // histogram with returned rank (mask kept in registers); NT loads
    i4v m4[EPT];
    unsigned rk[4 * EPT];
    const int vbase = (tile0 >> 2) + t;             // vec4 index, coalesced per j
    const i4v* mp = reinterpret_cast<const i4v*>(mask);
    #pragma unroll
    for (int j = 0; j < EPT; ++j)
        m4[j] = __builtin_nontemporal_load(&mp[vbase + BSA * j]);
    #pragma unroll
    for (int j = 0; j < EPT; ++j) {
        #pragma unroll
        for (int q = 0; q < 4; ++q) {
            unsigned lb = ((unsigned)m4[j][q] >> 13) & 2047u;
            rk[4 * j + q] = atomicAdd(&cnt[lb], 1u);
        }
    }
    __syncthreads();

    // exclusive scan over cnt[2048]: 2 per thread + wave64 shfl + cross-wave
    const int lane = t & 63, wid = t >> 6;
    unsigned c0 = cnt[2 * t], c1 = cnt[2 * t + 1];
    unsigned tsum = c0 + c1, x = tsum;
    #pragma unroll
    for (int off = 1; off < 64; off <<= 1) {
        unsigned y = __shfl_up(x, off, 64);
        if (lane >= off) x += y;
    }
    if (lane == 63) wsum[wid] = x;                  // wave totals
    __syncthreads();
    if (t < 16) {
        unsigned w = wsum[t];
        #pragma unroll
        for (int off = 1; off < 16; off <<= 1) {
            unsigned y = __shfl_up(w, off, 64);
            if (t >= off) w += y;
        }
        wsum[t] = w;                                // inclusive wave-prefix
    }
    __syncthreads();
    unsigned e0 = x - tsum + (wid ? wsum[wid - 1] : 0u);   // excl for 2t
    unsigned e1 = e0 + c0;                                 // excl for 2t+1
    pfx[2 * t]     = e0;
    pfx[2 * t + 1] = e1;
    // prefix table: u16 pair packed as one coalesced u32 store
    pfx_tab32[tile * (BPB / 2) + t] = (e0 & 0xFFFFu) | (e1 << 16);
    __syncthreads();

    // place records into srec in bucket-major order
    const f4v* up = reinterpret_cast<const f4v*>(upd);
    #pragma unroll
    for (int j = 0; j < EPT; ++j) {
        f4v u = __builtin_nontemporal_load(&up[vbase + BSA * j]);
        int cbase = (4 * (t + BSA * j)) & 63;       // channel of elem q=0
        #pragma unroll
        for (int q = 0; q < 4; ++q) {
            unsigned mm   = (unsigned)m4[j][q];
            unsigned lb   = (mm >> 13) & 2047u;
            unsigned lidx = (mm & 0x1FC0u) | (unsigned)(cbase + q);   // 13 bits
            unsigned pos  = pfx[lb] + rk[4 * j + q];
            u2v e; e[0] = lidx; e[1] = __float_as_uint(u[q]);
            srec[pos] = e;
        }
    }
    __syncthreads();

    // dense copy-out: the whole sorted tile as one contiguous 128 KB block.
    const uint4* s4 = reinterpret_cast<const uint4*>(srec);
    uint4* r4 = reinterpret_cast<uint4*>(rec + (size_t)tile0);
    #pragma unroll
    for (int j = 0; j < TILE / 2 / BSA; ++j)        // 8 x 16 B per thread
        r4[t + BSA * j] = s4[t + BSA * j];
}

// ---- Phase B: one run per thread, LDS accumulate, dense cached write ------
// 256 threads, 32 KB LDS -> ~4 WGs/CU, 64 WG-rounds/CU of pipelining.
__global__ __launch_bounds__(BSG)
void bucket_gather(const u2v* __restrict__ rec,
                   const unsigned short* __restrict__ pfx_tab,
                   float* __restrict__ out) {
    __shared__ float lds[8192];        // 32 KB = 128 pixels x 64 C

    const int t = threadIdx.x;
    const int bucket = blockIdx.x;
    const int batch  = bucket >> 11;
    const int b      = bucket & 2047;

    // issue this thread's run bounds FIRST (long-latency scattered u16 loads
    // overlap the LDS zeroing below)
    const int tile = (batch << 8) + t;              // thread t owns run of tile t
    const unsigned short* pt = pfx_tab + (size_t)tile * BPB;
    unsigned s = pt[b];
    unsigned e = (b == BPB - 1) ? (unsigned)TILE : pt[b + 1];
    const u2v* r = rec + (size_t)tile * TILE;

    f4v* lds4 = reinterpret_cast<f4v*>(lds);
    f4v z = {0.f, 0.f, 0.f, 0.f};
    #pragma unroll
    for (int k = 0; k < 8; ++k)                     // 2048 f4 / 256 thr
        lds4[t + BSG * k] = z;
    __syncthreads();

    // drain own run: independent iterations, no cross-lane state, good MLP
    for (unsigned i = s; i < e; ++i) {
        u2v rcd = __builtin_nontemporal_load(&r[i]);
        atomicAdd(&lds[rcd[0] & 8191u], __uint_as_float(rcd[1]));
    }
    __syncthreads();

    // dense output write (32 KB region, full-line, single-owner)
    size_t obase = ((size_t)batch << 24) + ((size_t)b << 13);
    f4v* out4 = reinterpret_cast<f4v*>(out + obase);
    #pragma unroll
    for (int k = 0; k < 8; ++k)
        out4[t + BSG * k] = lds4[t + BSG * k];
}

// ---- Fallback: direct atomic scatter (round-1) ----------------------------
__global__ void unpool_scatter(const float* __restrict__ upd,
                               const int*  __restrict__ mask,
                               float*      __restrict__ out) {
    int i = blockIdx.x * blockDim.x + threadIdx.x;
    int base = i << 2;
    if (base >= N_ELEM) return;
    const int4   m = reinterpret_cast<const int4*>(mask)[i];
    const float4 u = reinterpret_cast<const float4*>(upd)[i];
    int b = base >> 22;
    int c = base & 63;
    size_t obase = ((size_t)b << 24) + c;
    atomicAdd(&out[obase + (size_t)(m.x & ~63)    ], u.x);
    atomicAdd(&out[obase + (size_t)(m.y & ~63) + 1], u.y);
    atomicAdd(&out[obase + (size_t)(m.z & ~63) + 2], u.z);
    atomicAdd(&out[obase + (size_t)(m.w & ~63) + 3], u.w);
}

extern "C" void kernel_launch(void* const* d_in, const int* in_sizes, int n_in,
                              void* d_out, int out_size, void* d_ws, size_t ws_size,
                              hipStream_t stream) {
    const float* upd  = (const float*)d_in[0];
    const int*   mask = (const int*)d_in[1];
    float*       out  = (float*)d_out;

    if (ws_size < PFX_BYTES + REC_BYTES) {
        hipMemsetAsync(out, 0, (size_t)out_size * sizeof(float), stream);
        int n4 = N_ELEM / 4;
        unpool_scatter<<<(n4 + 255) / 256, 256, 0, stream>>>(upd, mask, out);
        return;
    }

    unsigned* pfx_tab32 = (unsigned*)d_ws;
    u2v*      rec       = (u2v*)((char*)d_ws + PFX_BYTES);

    // Opt in to >64 KB dynamic LDS (gfx950: 160 KB/CU). Non-stream call,
    // graph-capture-safe; deterministic.
    (void)hipFuncSetAttribute(reinterpret_cast<const void*>(bin16k),
                              hipFuncAttributeMaxDynamicSharedMemorySize,
                              (int)SREC_BYTES);

    bin16k<<<NTILE, BSA, SREC_BYTES, stream>>>(upd, mask, pfx_tab32, rec);
    bucket_gather<<<NBUCK, BSG, 0, stream>>>(rec, (const unsigned short*)pfx_tab32, out);
}

// Round 14
// 385.218 us; speedup vs baseline: 2.1849x; 2.1849x over previous
//
#include <hip/hip_runtime.h>

// MaxUnpooling2D scatter-add, fully deterministic two-phase (NO global atomics).
// updates [8,256,256,64] f32, mask int32 (flat index into [512*512*64] plane).
// out [8,512,512,64] f32, duplicates sum.
//
// dest flat (within batch plane) = (m & ~63) | c, c = element's own channel.
// bucket (global) = batch*1024 + (m>>14): 256 output pixels = 64 KB region.
// local idx in bucket = (m & 0x3FC0) | c, 14 bits.
//
// Phase A (bin16k): per 16384-elem tile, sort records by bucket in LDS and
//   write them as ONE dense contiguous 128 KB block + u16 prefix table.
// Phase B (bucket_gather): per bucket, wave-owned run ranges with monotone
//   run pointer; record reads are PLAIN CACHED loads (r13 post-mortem: the
//   nontemporal flag bypasses L2 allocation -> all record reads were L3
//   round-trips in r9-r12, pinning gather at ~300us across every variant).

static constexpr int PER_B  = 1 << 22;             // 4,194,304 elems/batch
static constexpr int NB     = 8;
static constexpr int N_ELEM = NB * PER_B;          // 33,554,432
static constexpr int BPB    = 1024;                // buckets per batch
static constexpr int NBUCK  = NB * BPB;            // 8192
static constexpr int TILE   = 16384;               // elements per bin WG
static constexpr int NTILE  = N_ELEM / TILE;       // 2048
static constexpr int TPB    = PER_B / TILE;        // 256 tiles (runs) per batch
static constexpr int EPT    = TILE / 4 / 1024;     // 4 vec4 loads per thread
static constexpr int BS     = 1024;                // threads per WG (16 waves)
static constexpr int RPW    = TPB / 16;            // 16 runs per wave
static constexpr size_t PFX_BYTES  = (size_t)NTILE * BPB * 2;  // 4 MB
static constexpr size_t REC_BYTES  = (size_t)N_ELEM * 8;       // 268.4 MB exact
static constexpr size_t SREC_BYTES = (size_t)TILE * 8;         // 128 KB dynamic LDS

typedef int      i4v __attribute__((ext_vector_type(4)));
typedef float    f4v __attribute__((ext_vector_type(4)));
typedef unsigned u2v __attribute__((ext_vector_type(2)));

// ---- Phase A: LDS multisplit -> dense per-tile record block + prefix table
// 1024 threads, 16 elems/thread, 128 KB dynamic srec -> 1 WG/CU, 16 waves.
__global__ __launch_bounds__(BS)
void bin16k(const float* __restrict__ upd,
            const int*  __restrict__ mask,
            unsigned short* __restrict__ pfx_tab,
            u2v*        __restrict__ rec) {
    __shared__ unsigned cnt[BPB];      // 4 KB
    __shared__ unsigned pfx[BPB];      // 4 KB exclusive prefix
    __shared__ unsigned wsum[16];      // wave partial sums
    extern __shared__ u2v srec[];      // 128 KB locally-sorted records

    const int t = threadIdx.x;
    const int tile  = blockIdx.x;
    const int tile0 = tile * TILE;                  // tile fully inside one batch

    cnt[t] = 0;                                     // BPB == BS
    __syncthreads();

    // histogram with returned rank (mask kept in registers); NT loads are fine
    // here: inputs are streamed once, fully consumed per wave instruction.
    i4v m4[EPT];
    unsigned rk[4 * EPT];
    const int vbase = (tile0 >> 2) + t;             // vec4 index, coalesced per j
    const i4v* mp = reinterpret_cast<const i4v*>(mask);
    #pragma unroll
    for (int j = 0; j < EPT; ++j)
        m4[j] = __builtin_nontemporal_load(&mp[vbase + BS * j]);
    #pragma unroll
    for (int j = 0; j < EPT; ++j) {
        #pragma unroll
        for (int q = 0; q < 4; ++q) {
            unsigned lb = ((unsigned)m4[j][q] >> 14) & 1023u;
            rk[4 * j + q] = atomicAdd(&cnt[lb], 1u);
        }
    }
    __syncthreads();

    // exclusive scan over cnt[1024]: wave64 shfl scan + cross-wave scan
    const int lane = t & 63, wid = t >> 6;
    unsigned v = cnt[t], x = v;
    #pragma unroll
    for (int off = 1; off < 64; off <<= 1) {
        unsigned y = __shfl_up(x, off, 64);
        if (lane >= off) x += y;
    }
    if (lane == 63) wsum[wid] = x;                  // wave totals
    __syncthreads();
    if (t < 16) {
        unsigned w = wsum[t];
        #pragma unroll
        for (int off = 1; off < 16; off <<= 1) {
            unsigned y = __shfl_up(w, off, 64);
            if (t >= off) w += y;
        }
        wsum[t] = w;                                // inclusive wave-prefix
    }
    __syncthreads();
    unsigned excl = x - v + (wid ? wsum[wid - 1] : 0u);
    pfx[t] = excl;
    // prefix table entry (u16, values <= 16384): coalesced 2 KB per tile
    pfx_tab[tile * BPB + t] = (unsigned short)excl;
    __syncthreads();

    // place records into srec in bucket-major order
    const f4v* up = reinterpret_cast<const f4v*>(upd);
    #pragma unroll
    for (int j = 0; j < EPT; ++j) {
        f4v u = __builtin_nontemporal_load(&up[vbase + BS * j]);
        int cbase = (4 * (t + BS * j)) & 63;        // channel of elem q=0
        #pragma unroll
        for (int q = 0; q < 4; ++q) {
            unsigned mm   = (unsigned)m4[j][q];
            unsigned lb   = (mm >> 14) & 1023u;
            unsigned lidx = (mm & 0x3FC0u) | (unsigned)(cbase + q);
            unsigned pos  = pfx[lb] + rk[4 * j + q];
            u2v e; e[0] = lidx; e[1] = __float_as_uint(u[q]);
            srec[pos] = e;
        }
    }
    __syncthreads();

    // dense copy-out: the whole sorted tile as one contiguous 128 KB block.
    // Plain cached stores (records should stay L2/L3-resident for gather).
    const uint4* s4 = reinterpret_cast<const uint4*>(srec);
    uint4* r4 = reinterpret_cast<uint4*>(rec + (size_t)tile0);
    #pragma unroll
    for (int j = 0; j < TILE / 2 / BS; ++j)         // 8 x 16 B per thread
        r4[t + BS * j] = s4[t + BS * j];
}

// ---- Phase B: per-bucket gather + LDS accumulate + dense cached write -----
// 1024 threads, ~66 KB LDS -> 2 WG/CU = 32 waves/CU.
// Each wave owns 16 consecutive runs; lanes walk consecutive ranks with a
// monotone run pointer (amortized ~1 LDS read per record).
__global__ __launch_bounds__(BS)
void bucket_gather(const u2v* __restrict__ rec,
                   const unsigned short* __restrict__ pfx_tab,
                   float* __restrict__ out) {
    __shared__ float    lds[16384];    // 64 KB = 256 pixels x 64 C
    __shared__ unsigned rstart[TPB];   // run start (global record idx)
    __shared__ unsigned rpfx[TPB + 1]; // exclusive prefix of run lengths
    __shared__ unsigned ws2[4];

    const int t = threadIdx.x;
    const int bucket = blockIdx.x;
    const int batch  = bucket >> 10;
    const int b      = bucket & 1023;

    f4v* lds4 = reinterpret_cast<f4v*>(lds);
    f4v z = {0.f, 0.f, 0.f, 0.f};
    #pragma unroll
    for (int k = 0; k < 4; ++k)
        lds4[t + BS * k] = z;

    // load this bucket's 256 run offsets; scan lengths (threads 0..255 = 4 waves)
    unsigned x = 0, len = 0;
    if (t < TPB) {
        int tile = (batch << 8) + t;
        unsigned s = pfx_tab[tile * BPB + b];
        unsigned e = (b == BPB - 1) ? (unsigned)TILE : pfx_tab[tile * BPB + b + 1];
        rstart[t] = (unsigned)tile * TILE + s;
        len = e - s;
        x = len;
        #pragma unroll
        for (int off = 1; off < 64; off <<= 1) {
            unsigned y = __shfl_up(x, off, 64);
            if ((t & 63) >= off) x += y;
        }
        if ((t & 63) == 63) ws2[t >> 6] = x;        // wave totals
    }
    __syncthreads();
    if (t == 0) {                                   // tiny serial cross-wave scan
        unsigned a = 0;
        #pragma unroll
        for (int i = 0; i < 4; ++i) { unsigned w = ws2[i]; ws2[i] = a; a += w; }
    }
    __syncthreads();
    if (t < TPB) {
        rpfx[t] = x - len + ws2[t >> 6];
        if (t == TPB - 1) rpfx[TPB] = ws2[3] + x;   // total
    }
    __syncthreads();

    // gather: wave w owns runs [RPW*w, RPW*(w+1)); lanes walk consecutive
    // ranks; run pointer advances monotonically (~1 LDS read per record).
    // Record loads are PLAIN CACHED (allocate in L2) — the r13 lesson.
    {
        const int w    = t >> 6;
        const int lane = t & 63;
        unsigned lo = (unsigned)(w * RPW);
        const unsigned k1 = rpfx[w * RPW + RPW];
        for (unsigned k = rpfx[w * RPW] + lane; k < k1; k += 64) {
            while (rpfx[lo + 1] <= k) ++lo;         // monotone advance
            u2v e = rec[rstart[lo] + (k - rpfx[lo])];
            atomicAdd(&lds[e[0] & 16383u], __uint_as_float(e[1]));
        }
    }
    __syncthreads();

    // dense output write: plain cached stores (full-line, single-owner region).
    size_t obase = ((size_t)batch << 24) + ((size_t)b << 14);
    f4v* out4 = reinterpret_cast<f4v*>(out + obase);
    #pragma unroll
    for (int k = 0; k < 4; ++k)
        out4[t + BS * k] = lds4[t + BS * k];
}

// ---- Fallback: direct atomic scatter (round-1) ----------------------------
__global__ void unpool_scatter(const float* __restrict__ upd,
                               const int*  __restrict__ mask,
                               float*      __restrict__ out) {
    int i = blockIdx.x * blockDim.x + threadIdx.x;
    int base = i << 2;
    if (base >= N_ELEM) return;
    const int4   m = reinterpret_cast<const int4*>(mask)[i];
    const float4 u = reinterpret_cast<const float4*>(upd)[i];
    int b = base >> 22;
    int c = base & 63;
    size_t obase = ((size_t)b << 24) + c;
    atomicAdd(&out[obase + (size_t)(m.x & ~63)    ], u.x);
    atomicAdd(&out[obase + (size_t)(m.y & ~63) + 1], u.y);
    atomicAdd(&out[obase + (size_t)(m.z & ~63) + 2], u.z);
    atomicAdd(&out[obase + (size_t)(m.w & ~63) + 3], u.w);
}

extern "C" void kernel_launch(void* const* d_in, const int* in_sizes, int n_in,
                              void* d_out, int out_size, void* d_ws, size_t ws_size,
                              hipStream_t stream) {
    const float* upd  = (const float*)d_in[0];
    const int*   mask = (const int*)d_in[1];
    float*       out  = (float*)d_out;

    if (ws_size < PFX_BYTES + REC_BYTES) {
        hipMemsetAsync(out, 0, (size_t)out_size * sizeof(float), stream);
        int n4 = N_ELEM / 4;
        unpool_scatter<<<(n4 + 255) / 256, 256, 0, stream>>>(upd, mask, out);
        return;
    }

    unsigned short* pfx_tab = (unsigned short*)d_ws;
    u2v*            rec     = (u2v*)((char*)d_ws + PFX_BYTES);

    // Opt in to >64 KB dynamic LDS (gfx950: 160 KB/CU). Non-stream call,
    // graph-capture-safe; deterministic.
    (void)hipFuncSetAttribute(reinterpret_cast<const void*>(bin16k),
                              hipFuncAttributeMaxDynamicSharedMemorySize,
                              (int)SREC_BYTES);

    bin16k<<<NTILE, BS, SREC_BYTES, stream>>>(upd, mask, pfx_tab, rec);
    bucket_gather<<<NBUCK, BS, 0, stream>>>(rec, pfx_tab, out);
}

// Round 15
// 344.880 us; speedup vs baseline: 2.4405x; 1.1170x over previous
//
#include <hip/hip_runtime.h>

// MaxUnpooling2D scatter-add, deterministic two-phase, 4-BYTE RECORDS.
// updates [8,256,256,64] f32, mask int32 (flat index into [512*512*64] plane).
// out [8,512,512,64] f32, duplicates sum.
//
// dest flat (within batch plane) = (m & ~63) | c, c = element's own channel.
// bucket (global) = batch*1024 + (m>>14): 256 output pixels = 64 KB region.
// local idx in bucket = (m & 0x3FC0) | c, 14 bits.
//
// RECORD = (f32 value bits rounded to 18-bit precision, low 14 bits = lidx).
//   encode: ((bits + 0x2000) & ~0x3FFF) | lidx   (RN on the magnitude)
//   decode: val = f32(rec & ~0x3FFF), lidx = rec & 0x3FFF
// Record array = 134 MB << 256 MB L3 (r14 post-mortem: 268 MB records thrashed
// L3 -> every gather variant was HBM-bound at ~300us; capacity, not code).

static constexpr int PER_B  = 1 << 22;             // 4,194,304 elems/batch
static constexpr int NB     = 8;
static constexpr int N_ELEM = NB * PER_B;          // 33,554,432
static constexpr int BPB    = 1024;                // buckets per batch
static constexpr int NBUCK  = NB * BPB;            // 8192
static constexpr int TILE   = 16384;               // elements per bin WG
static constexpr int NTILE  = N_ELEM / TILE;       // 2048
static constexpr int TPB    = PER_B / TILE;        // 256 tiles (runs) per batch
static constexpr int EPT    = TILE / 4 / 1024;     // 4 vec4 loads per thread
static constexpr int BS     = 1024;                // threads per WG (16 waves)
static constexpr int RPW    = TPB / 16;            // 16 runs per wave
static constexpr size_t PFX_BYTES  = (size_t)NTILE * BPB * 2;  // 4 MB
static constexpr size_t REC_BYTES  = (size_t)N_ELEM * 4;       // 134.2 MB
static constexpr size_t SREC_BYTES = (size_t)TILE * 4;         // 64 KB dynamic LDS

typedef int      i4v __attribute__((ext_vector_type(4)));
typedef float    f4v __attribute__((ext_vector_type(4)));

// ---- Phase A: LDS multisplit -> dense per-tile record block + prefix table
// 1024 threads, 16 elems/thread, ~8 KB static + 64 KB dynamic -> 2 WG/CU.
__global__ __launch_bounds__(BS)
void bin16k(const float* __restrict__ upd,
            const int*  __restrict__ mask,
            unsigned short* __restrict__ pfx_tab,
            unsigned*   __restrict__ rec) {
    __shared__ unsigned cnt[BPB];      // 4 KB
    __shared__ unsigned pfx[BPB];      // 4 KB exclusive prefix
    __shared__ unsigned wsum[16];      // wave partial sums
    extern __shared__ unsigned srec[]; // 64 KB locally-sorted 4B records

    const int t = threadIdx.x;
    const int tile  = blockIdx.x;
    const int tile0 = tile * TILE;                  // tile fully inside one batch

    cnt[t] = 0;                                     // BPB == BS
    __syncthreads();

    // histogram with returned rank (mask kept in registers); NT loads are fine
    // here: inputs are streamed once, fully consumed per wave instruction.
    i4v m4[EPT];
    unsigned rk[4 * EPT];
    const int vbase = (tile0 >> 2) + t;             // vec4 index, coalesced per j
    const i4v* mp = reinterpret_cast<const i4v*>(mask);
    #pragma unroll
    for (int j = 0; j < EPT; ++j)
        m4[j] = __builtin_nontemporal_load(&mp[vbase + BS * j]);
    #pragma unroll
    for (int j = 0; j < EPT; ++j) {
        #pragma unroll
        for (int q = 0; q < 4; ++q) {
            unsigned lb = ((unsigned)m4[j][q] >> 14) & 1023u;
            rk[4 * j + q] = atomicAdd(&cnt[lb], 1u);
        }
    }
    __syncthreads();

    // exclusive scan over cnt[1024]: wave64 shfl scan + cross-wave scan
    const int lane = t & 63, wid = t >> 6;
    unsigned v = cnt[t], x = v;
    #pragma unroll
    for (int off = 1; off < 64; off <<= 1) {
        unsigned y = __shfl_up(x, off, 64);
        if (lane >= off) x += y;
    }
    if (lane == 63) wsum[wid] = x;                  // wave totals
    __syncthreads();
    if (t < 16) {
        unsigned w = wsum[t];
        #pragma unroll
        for (int off = 1; off < 16; off <<= 1) {
            unsigned y = __shfl_up(w, off, 64);
            if (t >= off) w += y;
        }
        wsum[t] = w;                                // inclusive wave-prefix
    }
    __syncthreads();
    unsigned excl = x - v + (wid ? wsum[wid - 1] : 0u);
    pfx[t] = excl;
    // prefix table entry (u16, values <= 16384): coalesced 2 KB per tile
    pfx_tab[tile * BPB + t] = (unsigned short)excl;
    __syncthreads();

    // place 4B records into srec in bucket-major order
    const f4v* up = reinterpret_cast<const f4v*>(upd);
    #pragma unroll
    for (int j = 0; j < EPT; ++j) {
        f4v u = __builtin_nontemporal_load(&up[vbase + BS * j]);
        int cbase = (4 * (t + BS * j)) & 63;        // channel of elem q=0
        #pragma unroll
        for (int q = 0; q < 4; ++q) {
            unsigned mm   = (unsigned)m4[j][q];
            unsigned lb   = (mm >> 14) & 1023u;
            unsigned lidx = (mm & 0x3FC0u) | (unsigned)(cbase + q);
            unsigned pos  = pfx[lb] + rk[4 * j + q];
            unsigned vb   = __float_as_uint(u[q]);
            vb = (vb + 0x2000u) & 0xFFFFC000u;      // RN to 18-bit precision
            srec[pos] = vb | lidx;
        }
    }
    __syncthreads();

    // dense copy-out: the whole sorted tile as one contiguous 64 KB block.
    // Plain cached stores: records must stay L2/L3-resident for gather.
    const uint4* s4 = reinterpret_cast<const uint4*>(srec);
    uint4* r4 = reinterpret_cast<uint4*>(rec + (size_t)tile0);
    #pragma unroll
    for (int j = 0; j < TILE / 4 / BS; ++j)         // 4 x 16 B per thread
        r4[t + BS * j] = s4[t + BS * j];
}

// ---- Phase B: per-bucket gather + LDS accumulate + dense cached write -----
// 1024 threads, ~66 KB LDS -> 2 WG/CU = 32 waves/CU.
// Each wave owns 16 consecutive runs; lanes walk consecutive ranks with a
// monotone run pointer (amortized ~1 LDS read per record).
__global__ __launch_bounds__(BS)
void bucket_gather(const unsigned* __restrict__ rec,
                   const unsigned short* __restrict__ pfx_tab,
                   float* __restrict__ out) {
    __shared__ float    lds[16384];    // 64 KB = 256 pixels x 64 C
    __shared__ unsigned rstart[TPB];   // run start (global record idx)
    __shared__ unsigned rpfx[TPB + 1]; // exclusive prefix of run lengths
    __shared__ unsigned ws2[4];

    const int t = threadIdx.x;
    const int bucket = blockIdx.x;
    const int batch  = bucket >> 10;
    const int b      = bucket & 1023;

    f4v* lds4 = reinterpret_cast<f4v*>(lds);
    f4v z = {0.f, 0.f, 0.f, 0.f};
    #pragma unroll
    for (int k = 0; k < 4; ++k)
        lds4[t + BS * k] = z;

    // load this bucket's 256 run offsets; scan lengths (threads 0..255 = 4 waves)
    unsigned x = 0, len = 0;
    if (t < TPB) {
        int tile = (batch << 8) + t;
        unsigned s = pfx_tab[tile * BPB + b];
        unsigned e = (b == BPB - 1) ? (unsigned)TILE : pfx_tab[tile * BPB + b + 1];
        rstart[t] = (unsigned)tile * TILE + s;
        len = e - s;
        x = len;
        #pragma unroll
        for (int off = 1; off < 64; off <<= 1) {
            unsigned y = __shfl_up(x, off, 64);
            if ((t & 63) >= off) x += y;
        }
        if ((t & 63) == 63) ws2[t >> 6] = x;        // wave totals
    }
    __syncthreads();
    if (t == 0) {                                   // tiny serial cross-wave scan
        unsigned a = 0;
        #pragma unroll
        for (int i = 0; i < 4; ++i) { unsigned w = ws2[i]; ws2[i] = a; a += w; }
    }
    __syncthreads();
    if (t < TPB) {
        rpfx[t] = x - len + ws2[t >> 6];
        if (t == TPB - 1) rpfx[TPB] = ws2[3] + x;   // total
    }
    __syncthreads();

    // gather: wave w owns runs [RPW*w, RPW*(w+1)); lanes walk consecutive
    // ranks; run pointer advances monotonically. Plain cached 4B loads.
    {
        const int w    = t >> 6;
        const int lane = t & 63;
        unsigned lo = (unsigned)(w * RPW);
        const unsigned k1 = rpfx[w * RPW + RPW];
        for (unsigned k = rpfx[w * RPW] + lane; k < k1; k += 64) {
            while (rpfx[lo + 1] <= k) ++lo;         // monotone advance
            unsigned e = rec[rstart[lo] + (k - rpfx[lo])];
            atomicAdd(&lds[e & 16383u], __uint_as_float(e & 0xFFFFC000u));
        }
    }
    __syncthreads();

    // dense output write: plain cached stores (full-line, single-owner region).
    size_t obase = ((size_t)batch << 24) + ((size_t)b << 14);
    f4v* out4 = reinterpret_cast<f4v*>(out + obase);
    #pragma unroll
    for (int k = 0; k < 4; ++k)
        out4[t + BS * k] = lds4[t + BS * k];
}

// ---- Fallback: direct atomic scatter (round-1) ----------------------------
__global__ void unpool_scatter(const float* __restrict__ upd,
                               const int*  __restrict__ mask,
                               float*      __restrict__ out) {
    int i = blockIdx.x * blockDim.x + threadIdx.x;
    int base = i << 2;
    if (base >= N_ELEM) return;
    const int4   m = reinterpret_cast<const int4*>(mask)[i];
    const float4 u = reinterpret_cast<const float4*>(upd)[i];
    int b = base >> 22;
    int c = base & 63;
    size_t obase = ((size_t)b << 24) + c;
    atomicAdd(&out[obase + (size_t)(m.x & ~63)    ], u.x);
    atomicAdd(&out[obase + (size_t)(m.y & ~63) + 1], u.y);
    atomicAdd(&out[obase + (size_t)(m.z & ~63) + 2], u.z);
    atomicAdd(&out[obase + (size_t)(m.w & ~63) + 3], u.w);
}

extern "C" void kernel_launch(void* const* d_in, const int* in_sizes, int n_in,
                              void* d_out, int out_size, void* d_ws, size_t ws_size,
                              hipStream_t stream) {
    const float* upd  = (const float*)d_in[0];
    const int*   mask = (const int*)d_in[1];
    float*       out  = (float*)d_out;

    if (ws_size < PFX_BYTES + REC_BYTES) {
        hipMemsetAsync(out, 0, (size_t)out_size * sizeof(float), stream);
        int n4 = N_ELEM / 4;
        unpool_scatter<<<(n4 + 255) / 256, 256, 0, stream>>>(upd, mask, out);
        return;
    }

    unsigned short* pfx_tab = (unsigned short*)d_ws;
    unsigned*       rec     = (unsigned*)((char*)d_ws + PFX_BYTES);

    bin16k<<<NTILE, BS, SREC_BYTES, stream>>>(upd, mask, pfx_tab, rec);
    bucket_gather<<<NBUCK, BS, 0, stream>>>(rec, pfx_tab, out);
}

// Round 16
// 327.896 us; speedup vs baseline: 2.5669x; 1.0518x over previous
//
#include <hip/hip_runtime.h>

// MaxUnpooling2D scatter-add, deterministic two-phase, 4-BYTE RECORDS.
// updates [8,256,256,64] f32, mask int32 (flat index into [512*512*64] plane).
// out [8,512,512,64] f32, duplicates sum.
//
// dest flat (within batch plane) = (m & ~63) | c, c = element's own channel.
// bucket (global) = batch*1024 + (m>>14): 256 output pixels = 64 KB region.
// local idx in bucket = (m & 0x3FC0) | c, 14 bits.
//
// RECORD = (f32 value bits rounded to 18-bit precision, low 14 bits = lidx).
//   encode: ((bits + 0x2000) & ~0x3FFF) | lidx   (RN on the magnitude)
//   decode: val = f32(rec & ~0x3FFF), lidx = rec & 0x3FFF
// Record array = 134 MB << 256 MB L3 (r15: L3-residency was worth -40us).
//
// Phase B gather (r15 post-mortem): k+=64 per lane forced ~4 dependent LDS
// while-reads per record. Now each THREAD owns a contiguous rank range
// (~16 ranks = ~1 run = one 64 B line): one binary search per thread, ~1
// while-check per record, sequential per-lane addresses, independent lanes.

static constexpr int PER_B  = 1 << 22;             // 4,194,304 elems/batch
static constexpr int NB     = 8;
static constexpr int N_ELEM = NB * PER_B;          // 33,554,432
static constexpr int BPB    = 1024;                // buckets per batch
static constexpr int NBUCK  = NB * BPB;            // 8192
static constexpr int TILE   = 16384;               // elements per bin WG
static constexpr int NTILE  = N_ELEM / TILE;       // 2048
static constexpr int TPB    = PER_B / TILE;        // 256 tiles (runs) per batch
static constexpr int EPT    = TILE / 4 / 1024;     // 4 vec4 loads per thread
static constexpr int BS     = 1024;                // threads per WG (16 waves)
static constexpr size_t PFX_BYTES  = (size_t)NTILE * BPB * 2;  // 4 MB
static constexpr size_t REC_BYTES  = (size_t)N_ELEM * 4;       // 134.2 MB
static constexpr size_t SREC_BYTES = (size_t)TILE * 4;         // 64 KB dynamic LDS

typedef int      i4v __attribute__((ext_vector_type(4)));
typedef float    f4v __attribute__((ext_vector_type(4)));

// ---- Phase A: LDS multisplit -> dense per-tile record block + prefix table
// 1024 threads, 16 elems/thread, ~8 KB static + 64 KB dynamic -> 2 WG/CU.
__global__ __launch_bounds__(BS)
void bin16k(const float* __restrict__ upd,
            const int*  __restrict__ mask,
            unsigned short* __restrict__ pfx_tab,
            unsigned*   __restrict__ rec) {
    __shared__ unsigned cnt[BPB];      // 4 KB
    __shared__ unsigned pfx[BPB];      // 4 KB exclusive prefix
    __shared__ unsigned wsum[16];      // wave partial sums
    extern __shared__ unsigned srec[]; // 64 KB locally-sorted 4B records

    const int t = threadIdx.x;
    const int tile  = blockIdx.x;
    const int tile0 = tile * TILE;                  // tile fully inside one batch

    cnt[t] = 0;                                     // BPB == BS
    __syncthreads();

    // histogram with returned rank (mask kept in registers); NT loads are fine
    // here: inputs are streamed once, fully consumed per wave instruction.
    i4v m4[EPT];
    unsigned rk[4 * EPT];
    const int vbase = (tile0 >> 2) + t;             // vec4 index, coalesced per j
    const i4v* mp = reinterpret_cast<const i4v*>(mask);
    #pragma unroll
    for (int j = 0; j < EPT; ++j)
        m4[j] = __builtin_nontemporal_load(&mp[vbase + BS * j]);
    #pragma unroll
    for (int j = 0; j < EPT; ++j) {
        #pragma unroll
        for (int q = 0; q < 4; ++q) {
            unsigned lb = ((unsigned)m4[j][q] >> 14) & 1023u;
            rk[4 * j + q] = atomicAdd(&cnt[lb], 1u);
        }
    }
    __syncthreads();

    // exclusive scan over cnt[1024]: wave64 shfl scan + cross-wave scan
    const int lane = t & 63, wid = t >> 6;
    unsigned v = cnt[t], x = v;
    #pragma unroll
    for (int off = 1; off < 64; off <<= 1) {
        unsigned y = __shfl_up(x, off, 64);
        if (lane >= off) x += y;
    }
    if (lane == 63) wsum[wid] = x;                  // wave totals
    __syncthreads();
    if (t < 16) {
        unsigned w = wsum[t];
        #pragma unroll
        for (int off = 1; off < 16; off <<= 1) {
            unsigned y = __shfl_up(w, off, 64);
            if (t >= off) w += y;
        }
        wsum[t] = w;                                // inclusive wave-prefix
    }
    __syncthreads();
    unsigned excl = x - v + (wid ? wsum[wid - 1] : 0u);
    pfx[t] = excl;
    // prefix table entry (u16, values <= 16384): coalesced 2 KB per tile
    pfx_tab[tile * BPB + t] = (unsigned short)excl;
    __syncthreads();

    // place 4B records into srec in bucket-major order
    const f4v* up = reinterpret_cast<const f4v*>(upd);
    #pragma unroll
    for (int j = 0; j < EPT; ++j) {
        f4v u = __builtin_nontemporal_load(&up[vbase + BS * j]);
        int cbase = (4 * (t + BS * j)) & 63;        // channel of elem q=0
        #pragma unroll
        for (int q = 0; q < 4; ++q) {
            unsigned mm   = (unsigned)m4[j][q];
            unsigned lb   = (mm >> 14) & 1023u;
            unsigned lidx = (mm & 0x3FC0u) | (unsigned)(cbase + q);
            unsigned pos  = pfx[lb] + rk[4 * j + q];
            unsigned vb   = __float_as_uint(u[q]);
            vb = (vb + 0x2000u) & 0xFFFFC000u;      // RN to 18-bit precision
            srec[pos] = vb | lidx;
        }
    }
    __syncthreads();

    // dense copy-out: the whole sorted tile as one contiguous 64 KB block.
    // Plain cached stores: records must stay L2/L3-resident for gather.
    const uint4* s4 = reinterpret_cast<const uint4*>(srec);
    uint4* r4 = reinterpret_cast<uint4*>(rec + (size_t)tile0);
    #pragma unroll
    for (int j = 0; j < TILE / 4 / BS; ++j)         // 4 x 16 B per thread
        r4[t + BS * j] = s4[t + BS * j];
}

// ---- Phase B: per-bucket gather + LDS accumulate + dense cached write -----
// 1024 threads, ~66 KB LDS -> 2 WG/CU = 32 waves/CU.
// Thread t owns contiguous ranks [T*t/1024, T*(t+1)/1024): one binary search,
// then monotone walk with ~1 LDS check/record; per-lane sequential addresses.
__global__ __launch_bounds__(BS)
void bucket_gather(const unsigned* __restrict__ rec,
                   const unsigned short* __restrict__ pfx_tab,
                   float* __restrict__ out) {
    __shared__ float    lds[16384];    // 64 KB = 256 pixels x 64 C
    __shared__ unsigned rstart[TPB];   // run start (global record idx)
    __shared__ unsigned rpfx[TPB + 1]; // exclusive prefix of run lengths
    __shared__ unsigned ws2[4];

    const int t = threadIdx.x;
    const int bucket = blockIdx.x;
    const int batch  = bucket >> 10;
    const int b      = bucket & 1023;

    f4v* lds4 = reinterpret_cast<f4v*>(lds);
    f4v z = {0.f, 0.f, 0.f, 0.f};
    #pragma unroll
    for (int k = 0; k < 4; ++k)
        lds4[t + BS * k] = z;

    // load this bucket's 256 run offsets; scan lengths (threads 0..255 = 4 waves)
    unsigned x = 0, len = 0;
    if (t < TPB) {
        int tile = (batch << 8) + t;
        unsigned s = pfx_tab[tile * BPB + b];
        unsigned e = (b == BPB - 1) ? (unsigned)TILE : pfx_tab[tile * BPB + b + 1];
        rstart[t] = (unsigned)tile * TILE + s;
        len = e - s;
        x = len;
        #pragma unroll
        for (int off = 1; off < 64; off <<= 1) {
            unsigned y = __shfl_up(x, off, 64);
            if ((t & 63) >= off) x += y;
        }
        if ((t & 63) == 63) ws2[t >> 6] = x;        // wave totals
    }
    __syncthreads();
    if (t == 0) {                                   // tiny serial cross-wave scan
        unsigned a = 0;
        #pragma unroll
        for (int i = 0; i < 4; ++i) { unsigned w = ws2[i]; ws2[i] = a; a += w; }
    }
    __syncthreads();
    if (t < TPB) {
        rpfx[t] = x - len + ws2[t >> 6];
        if (t == TPB - 1) rpfx[TPB] = ws2[3] + x;   // total
    }
    __syncthreads();

    // gather: thread t owns ranks [T*t>>10, T*(t+1)>>10) (~16 consecutive).
    {
        const unsigned T  = rpfx[TPB];
        unsigned k0 = (T * (unsigned)t) >> 10;
        unsigned k1 = (T * ((unsigned)t + 1u)) >> 10;
        // one binary search for the starting run (8 steps)
        unsigned lo = 0, hi = TPB;
        while (hi - lo > 1) {
            unsigned mid = (lo + hi) >> 1;
            if (rpfx[mid] <= k0) lo = mid; else hi = mid;
        }
        for (unsigned k = k0; k < k1; ++k) {
            while (rpfx[lo + 1] <= k) ++lo;         // ~1 check per record
            unsigned e = rec[rstart[lo] + (k - rpfx[lo])];
            atomicAdd(&lds[e & 16383u], __uint_as_float(e & 0xFFFFC000u));
        }
    }
    __syncthreads();

    // dense output write: plain cached stores (full-line, single-owner region).
    size_t obase = ((size_t)batch << 24) + ((size_t)b << 14);
    f4v* out4 = reinterpret_cast<f4v*>(out + obase);
    #pragma unroll
    for (int k = 0; k < 4; ++k)
        out4[t + BS * k] = lds4[t + BS * k];
}

// ---- Fallback: direct atomic scatter (round-1) ----------------------------
__global__ void unpool_scatter(const float* __restrict__ upd,
                               const int*  __restrict__ mask,
                               float*      __restrict__ out) {
    int i = blockIdx.x * blockDim.x + threadIdx.x;
    int base = i << 2;
    if (base >= N_ELEM) return;
    const int4   m = reinterpret_cast<const int4*>(mask)[i];
    const float4 u = reinterpret_cast<const float4*>(upd)[i];
    int b = base >> 22;
    int c = base & 63;
    size_t obase = ((size_t)b << 24) + c;
    atomicAdd(&out[obase + (size_t)(m.x & ~63)    ], u.x);
    atomicAdd(&out[obase + (size_t)(m.y & ~63) + 1], u.y);
    atomicAdd(&out[obase + (size_t)(m.z & ~63) + 2], u.z);
    atomicAdd(&out[obase + (size_t)(m.w & ~63) + 3], u.w);
}

extern "C" void kernel_launch(void* const* d_in, const int* in_sizes, int n_in,
                              void* d_out, int out_size, void* d_ws, size_t ws_size,
                              hipStream_t stream) {
    const float* upd  = (const float*)d_in[0];
    const int*   mask = (const int*)d_in[1];
    float*       out  = (float*)d_out;

    if (ws_size < PFX_BYTES + REC_BYTES) {
        hipMemsetAsync(out, 0, (size_t)out_size * sizeof(float), stream);
        int n4 = N_ELEM / 4;
        unpool_scatter<<<(n4 + 255) / 256, 256, 0, stream>>>(upd, mask, out);
        return;
    }

    unsigned short* pfx_tab = (unsigned short*)d_ws;
    unsigned*       rec     = (unsigned*)((char*)d_ws + PFX_BYTES);

    bin16k<<<NTILE, BS, SREC_BYTES, stream>>>(upd, mask, pfx_tab, rec);
    bucket_gather<<<NBUCK, BS, 0, stream>>>(rec, pfx_tab, out);
}

// Round 17
// 299.314 us; speedup vs baseline: 2.8120x; 1.0955x over previous
//
#include <hip/hip_runtime.h>

// MaxUnpooling2D scatter-add, deterministic two-phase, 4-BYTE RECORDS.
// updates [8,256,256,64] f32, mask int32 (flat index into [512*512*64] plane).
// out [8,512,512,64] f32, duplicates sum.
//
// dest flat (within batch plane) = (m & ~63) | c, c = element's own channel.
// bucket (global) = batch*1024 + (m>>14): 256 output pixels = 64 KB region.
// local idx in bucket = (m & 0x3FC0) | c, 14 bits.
//
// RECORD = (f32 value bits rounded to 18-bit precision, low 14 bits = lidx).
//   encode: ((bits + 0x2000) & ~0x3FFF) | lidx   (RN on the magnitude)
//   decode: val = f32(rec & ~0x3FFF), lidx = rec & 0x3FFF
// Record array = 134 MB << 256 MB L3 (r15: L3-residency -40us).
//
// Phase B (r16 post-mortem): rank-range walk still paid ~1 dependent LDS read
// per record. A run averages 16 records = 64 B = ONE line. New layout: thread
// t serves run t>>2, portion t&3 -> lanes 4r..4r+3 read the SAME line
// (merged), ~16 lines/wave/iter, ZERO in-loop LDS reads, independent iters.
// Prefix-scan preamble deleted entirely.

static constexpr int PER_B  = 1 << 22;             // 4,194,304 elems/batch
static constexpr int NB     = 8;
static constexpr int N_ELEM = NB * PER_B;          // 33,554,432
static constexpr int BPB    = 1024;                // buckets per batch
static constexpr int NBUCK  = NB * BPB;            // 8192
static constexpr int TILE   = 16384;               // elements per bin WG
static constexpr int NTILE  = N_ELEM / TILE;       // 2048
static constexpr int TPB    = PER_B / TILE;        // 256 tiles (runs) per batch
static constexpr int EPT    = TILE / 4 / 1024;     // 4 vec4 loads per thread
static constexpr int BS     = 1024;                // threads per WG (16 waves)
static constexpr size_t PFX_BYTES  = (size_t)NTILE * BPB * 2;  // 4 MB
static constexpr size_t REC_BYTES  = (size_t)N_ELEM * 4;       // 134.2 MB
static constexpr size_t SREC_BYTES = (size_t)TILE * 4;         // 64 KB dynamic LDS

typedef int      i4v __attribute__((ext_vector_type(4)));
typedef float    f4v __attribute__((ext_vector_type(4)));

// ---- Phase A: LDS multisplit -> dense per-tile record block + prefix table
// 1024 threads, 16 elems/thread, ~8 KB static + 64 KB dynamic -> 2 WG/CU.
__global__ __launch_bounds__(BS)
void bin16k(const float* __restrict__ upd,
            const int*  __restrict__ mask,
            unsigned short* __restrict__ pfx_tab,
            unsigned*   __restrict__ rec) {
    __shared__ unsigned cnt[BPB];      // 4 KB
    __shared__ unsigned pfx[BPB];      // 4 KB exclusive prefix
    __shared__ unsigned wsum[16];      // wave partial sums
    extern __shared__ unsigned srec[]; // 64 KB locally-sorted 4B records

    const int t = threadIdx.x;
    const int tile  = blockIdx.x;
    const int tile0 = tile * TILE;                  // tile fully inside one batch

    cnt[t] = 0;                                     // BPB == BS
    __syncthreads();

    // histogram with returned rank (mask kept in registers); NT loads are fine
    // here: inputs are streamed once, fully consumed per wave instruction.
    i4v m4[EPT];
    unsigned rk[4 * EPT];
    const int vbase = (tile0 >> 2) + t;             // vec4 index, coalesced per j
    const i4v* mp = reinterpret_cast<const i4v*>(mask);
    #pragma unroll
    for (int j = 0; j < EPT; ++j)
        m4[j] = __builtin_nontemporal_load(&mp[vbase + BS * j]);
    #pragma unroll
    for (int j = 0; j < EPT; ++j) {
        #pragma unroll
        for (int q = 0; q < 4; ++q) {
            unsigned lb = ((unsigned)m4[j][q] >> 14) & 1023u;
            rk[4 * j + q] = atomicAdd(&cnt[lb], 1u);
        }
    }
    __syncthreads();

    // exclusive scan over cnt[1024]: wave64 shfl scan + cross-wave scan
    const int lane = t & 63, wid = t >> 6;
    unsigned v = cnt[t], x = v;
    #pragma unroll
    for (int off = 1; off < 64; off <<= 1) {
        unsigned y = __shfl_up(x, off, 64);
        if (lane >= off) x += y;
    }
    if (lane == 63) wsum[wid] = x;                  // wave totals
    __syncthreads();
    if (t < 16) {
        unsigned w = wsum[t];
        #pragma unroll
        for (int off = 1; off < 16; off <<= 1) {
            unsigned y = __shfl_up(w, off, 64);
            if (t >= off) w += y;
        }
        wsum[t] = w;                                // inclusive wave-prefix
    }
    __syncthreads();
    unsigned excl = x - v + (wid ? wsum[wid - 1] : 0u);
    pfx[t] = excl;
    // prefix table entry (u16, values <= 16384): coalesced 2 KB per tile
    pfx_tab[tile * BPB + t] = (unsigned short)excl;
    __syncthreads();

    // place 4B records into srec in bucket-major order
    const f4v* up = reinterpret_cast<const f4v*>(upd);
    #pragma unroll
    for (int j = 0; j < EPT; ++j) {
        f4v u = __builtin_nontemporal_load(&up[vbase + BS * j]);
        int cbase = (4 * (t + BS * j)) & 63;        // channel of elem q=0
        #pragma unroll
        for (int q = 0; q < 4; ++q) {
            unsigned mm   = (unsigned)m4[j][q];
            unsigned lb   = (mm >> 14) & 1023u;
            unsigned lidx = (mm & 0x3FC0u) | (unsigned)(cbase + q);
            unsigned pos  = pfx[lb] + rk[4 * j + q];
            unsigned vb   = __float_as_uint(u[q]);
            vb = (vb + 0x2000u) & 0xFFFFC000u;      // RN to 18-bit precision
            srec[pos] = vb | lidx;
        }
    }
    __syncthreads();

    // dense copy-out: the whole sorted tile as one contiguous 64 KB block.
    // Plain cached stores: records must stay L2/L3-resident for gather.
    const uint4* s4 = reinterpret_cast<const uint4*>(srec);
    uint4* r4 = reinterpret_cast<uint4*>(rec + (size_t)tile0);
    #pragma unroll
    for (int j = 0; j < TILE / 4 / BS; ++j)         // 4 x 16 B per thread
        r4[t + BS * j] = s4[t + BS * j];
}

// ---- Phase B: per-bucket gather + LDS accumulate + dense cached write -----
// 1024 threads, ~66 KB LDS -> 2 WG/CU = 32 waves/CU.
// Thread t serves run t>>2, portion t&3 (runs avg 16 recs = 64 B = 1 line;
// the 4 sibling lanes share that line). No in-loop LDS reads, no scan.
__global__ __launch_bounds__(BS)
void bucket_gather(const unsigned* __restrict__ rec,
                   const unsigned short* __restrict__ pfx_tab,
                   float* __restrict__ out) {
    __shared__ float    lds[16384];    // 64 KB = 256 pixels x 64 C
    __shared__ unsigned rstart[TPB];   // run start (global record idx)
    __shared__ unsigned short rlen[TPB];

    const int t = threadIdx.x;
    const int bucket = blockIdx.x;
    const int batch  = bucket >> 10;
    const int b      = bucket & 1023;

    // issue run-bound loads FIRST (scattered u16 pairs; latency overlaps zeroing)
    if (t < TPB) {
        int tile = (batch << 8) + t;
        unsigned s = pfx_tab[tile * BPB + b];
        unsigned e = (b == BPB - 1) ? (unsigned)TILE : pfx_tab[tile * BPB + b + 1];
        rstart[t] = (unsigned)tile * TILE + s;
        rlen[t]   = (unsigned short)(e - s);
    }

    f4v* lds4 = reinterpret_cast<f4v*>(lds);
    f4v z = {0.f, 0.f, 0.f, 0.f};
    #pragma unroll
    for (int k = 0; k < 4; ++k)
        lds4[t + BS * k] = z;
    __syncthreads();

    // drain: run = t>>2, portion = t&3. ~4 records each, independent iters.
    {
        const unsigned run = (unsigned)t >> 2;
        const unsigned p   = (unsigned)t & 3u;
        const unsigned len = rlen[run];
        const unsigned q0  = (len * p) >> 2;
        const unsigned q1  = (len * (p + 1u)) >> 2;
        const unsigned* r = rec + rstart[run];
        for (unsigned i = q0; i < q1; ++i) {
            unsigned e = r[i];
            atomicAdd(&lds[e & 16383u], __uint_as_float(e & 0xFFFFC000u));
        }
    }
    __syncthreads();

    // dense output write: plain cached stores (full-line, single-owner region).
    size_t obase = ((size_t)batch << 24) + ((size_t)b << 14);
    f4v* out4 = reinterpret_cast<f4v*>(out + obase);
    #pragma unroll
    for (int k = 0; k < 4; ++k)
        out4[t + BS * k] = lds4[t + BS * k];
}

// ---- Fallback: direct atomic scatter (round-1) ----------------------------
__global__ void unpool_scatter(const float* __restrict__ upd,
                               const int*  __restrict__ mask,
                               float*      __restrict__ out) {
    int i = blockIdx.x * blockDim.x + threadIdx.x;
    int base = i << 2;
    if (base >= N_ELEM) return;
    const int4   m = reinterpret_cast<const int4*>(mask)[i];
    const float4 u = reinterpret_cast<const float4*>(upd)[i];
    int b = base >> 22;
    int c = base & 63;
    size_t obase = ((size_t)b << 24) + c;
    atomicAdd(&out[obase + (size_t)(m.x & ~63)    ], u.x);
    atomicAdd(&out[obase + (size_t)(m.y & ~63) + 1], u.y);
    atomicAdd(&out[obase + (size_t)(m.z & ~63) + 2], u.z);
    atomicAdd(&out[obase + (size_t)(m.w & ~63) + 3], u.w);
}

extern "C" void kernel_launch(void* const* d_in, const int* in_sizes, int n_in,
                              void* d_out, int out_size, void* d_ws, size_t ws_size,
                              hipStream_t stream) {
    const float* upd  = (const float*)d_in[0];
    const int*   mask = (const int*)d_in[1];
    float*       out  = (float*)d_out;

    if (ws_size < PFX_BYTES + REC_BYTES) {
        hipMemsetAsync(out, 0, (size_t)out_size * sizeof(float), stream);
        int n4 = N_ELEM / 4;
        unpool_scatter<<<(n4 + 255) / 256, 256, 0, stream>>>(upd, mask, out);
        return;
    }

    unsigned short* pfx_tab = (unsigned short*)d_ws;
    unsigned*       rec     = (unsigned*)((char*)d_ws + PFX_BYTES);

    bin16k<<<NTILE, BS, SREC_BYTES, stream>>>(upd, mask, pfx_tab, rec);
    bucket_gather<<<NBUCK, BS, 0, stream>>>(rec, pfx_tab, out);
}

// Round 18
// 277.249 us; speedup vs baseline: 3.0358x; 1.0796x over previous
//
#include <hip/hip_runtime.h>

// MaxUnpooling2D scatter-add, deterministic two-phase, 4-BYTE RECORDS.
// updates [8,256,256,64] f32, mask int32 (flat index into [512*512*64] plane).
// out [8,512,512,64] f32, duplicates sum.
//
// dest flat (within batch plane) = (m & ~63) | c, c = element's own channel.
// bucket (global) = batch*1024 + (m>>14): 256 output pixels = 64 KB region.
// local idx in bucket = (m & 0x3FC0) | c, 14 bits.
//
// RECORD = (f32 value bits rounded to 18-bit precision, low 14 bits = lidx).
//   encode: ((bits + 0x2000) & ~0x3FFF) | lidx   (RN on the magnitude)
//   decode: val = f32(rec & ~0x3FFF), lidx = rec & 0x3FFF
// Record array = 134 MB < 256 MB L3 (r15: L3-residency -40us).
//
// Phase B: thread t serves run t>>2, portion t&3 (runs avg 16 recs = 64 B =
// ONE line; 4 sibling lanes share it, merged). No in-loop LDS reads (r17:
// -29us). Output written with NONTEMPORAL stores so the 512 MB stream does
// not evict the L3-resident record array between bin-write and gather-read
// (r11's NT-neutral result was measured when records were 268 MB and
// thrashed L3 regardless; with 134 MB the interaction flips).

static constexpr int PER_B  = 1 << 22;             // 4,194,304 elems/batch
static constexpr int NB     = 8;
static constexpr int N_ELEM = NB * PER_B;          // 33,554,432
static constexpr int BPB    = 1024;                // buckets per batch
static constexpr int NBUCK  = NB * BPB;            // 8192
static constexpr int TILE   = 16384;               // elements per bin WG
static constexpr int NTILE  = N_ELEM / TILE;       // 2048
static constexpr int TPB    = PER_B / TILE;        // 256 tiles (runs) per batch
static constexpr int EPT    = TILE / 4 / 1024;     // 4 vec4 loads per thread
static constexpr int BS     = 1024;                // threads per WG (16 waves)
static constexpr size_t PFX_BYTES  = (size_t)NTILE * BPB * 2;  // 4 MB
static constexpr size_t REC_BYTES  = (size_t)N_ELEM * 4;       // 134.2 MB
static constexpr size_t SREC_BYTES = (size_t)TILE * 4;         // 64 KB dynamic LDS

typedef int      i4v __attribute__((ext_vector_type(4)));
typedef float    f4v __attribute__((ext_vector_type(4)));

// ---- Phase A: LDS multisplit -> dense per-tile record block + prefix table
// 1024 threads, 16 elems/thread, ~8 KB static + 64 KB dynamic -> 2 WG/CU.
__global__ __launch_bounds__(BS)
void bin16k(const float* __restrict__ upd,
            const int*  __restrict__ mask,
            unsigned short* __restrict__ pfx_tab,
            unsigned*   __restrict__ rec) {
    __shared__ unsigned cnt[BPB];      // 4 KB
    __shared__ unsigned pfx[BPB];      // 4 KB exclusive prefix
    __shared__ unsigned wsum[16];      // wave partial sums
    extern __shared__ unsigned srec[]; // 64 KB locally-sorted 4B records

    const int t = threadIdx.x;
    const int tile  = blockIdx.x;
    const int tile0 = tile * TILE;                  // tile fully inside one batch

    cnt[t] = 0;                                     // BPB == BS
    __syncthreads();

    // histogram with returned rank (mask kept in registers); NT loads are fine
    // here: inputs are streamed once, fully consumed per wave instruction.
    i4v m4[EPT];
    unsigned rk[4 * EPT];
    const int vbase = (tile0 >> 2) + t;             // vec4 index, coalesced per j
    const i4v* mp = reinterpret_cast<const i4v*>(mask);
    #pragma unroll
    for (int j = 0; j < EPT; ++j)
        m4[j] = __builtin_nontemporal_load(&mp[vbase + BS * j]);
    #pragma unroll
    for (int j = 0; j < EPT; ++j) {
        #pragma unroll
        for (int q = 0; q < 4; ++q) {
            unsigned lb = ((unsigned)m4[j][q] >> 14) & 1023u;
            rk[4 * j + q] = atomicAdd(&cnt[lb], 1u);
        }
    }
    __syncthreads();

    // exclusive scan over cnt[1024]: wave64 shfl scan + cross-wave scan
    const int lane = t & 63, wid = t >> 6;
    unsigned v = cnt[t], x = v;
    #pragma unroll
    for (int off = 1; off < 64; off <<= 1) {
        unsigned y = __shfl_up(x, off, 64);
        if (lane >= off) x += y;
    }
    if (lane == 63) wsum[wid] = x;                  // wave totals
    __syncthreads();
    if (t < 16) {
        unsigned w = wsum[t];
        #pragma unroll
        for (int off = 1; off < 16; off <<= 1) {
            unsigned y = __shfl_up(w, off, 64);
            if (t >= off) w += y;
        }
        wsum[t] = w;                                // inclusive wave-prefix
    }
    __syncthreads();
    unsigned excl = x - v + (wid ? wsum[wid - 1] : 0u);
    pfx[t] = excl;
    // prefix table entry (u16, values <= 16384): coalesced 2 KB per tile
    pfx_tab[tile * BPB + t] = (unsigned short)excl;
    __syncthreads();

    // place 4B records into srec in bucket-major order
    const f4v* up = reinterpret_cast<const f4v*>(upd);
    #pragma unroll
    for (int j = 0; j < EPT; ++j) {
        f4v u = __builtin_nontemporal_load(&up[vbase + BS * j]);
        int cbase = (4 * (t + BS * j)) & 63;        // channel of elem q=0
        #pragma unroll
        for (int q = 0; q < 4; ++q) {
            unsigned mm   = (unsigned)m4[j][q];
            unsigned lb   = (mm >> 14) & 1023u;
            unsigned lidx = (mm & 0x3FC0u) | (unsigned)(cbase + q);
            unsigned pos  = pfx[lb] + rk[4 * j + q];
            unsigned vb   = __float_as_uint(u[q]);
            vb = (vb + 0x2000u) & 0xFFFFC000u;      // RN to 18-bit precision
            srec[pos] = vb | lidx;
        }
    }
    __syncthreads();

    // dense copy-out: the whole sorted tile as one contiguous 64 KB block.
    // Plain cached stores: records must stay L2/L3-resident for gather.
    const uint4* s4 = reinterpret_cast<const uint4*>(srec);
    uint4* r4 = reinterpret_cast<uint4*>(rec + (size_t)tile0);
    #pragma unroll
    for (int j = 0; j < TILE / 4 / BS; ++j)         // 4 x 16 B per thread
        r4[t + BS * j] = s4[t + BS * j];
}

// ---- Phase B: per-bucket gather + LDS accumulate + dense NT write ---------
// 1024 threads, ~66 KB LDS -> 2 WG/CU = 32 waves/CU.
// Thread t serves run t>>2, portion t&3; no in-loop LDS reads, no scan.
__global__ __launch_bounds__(BS)
void bucket_gather(const unsigned* __restrict__ rec,
                   const unsigned short* __restrict__ pfx_tab,
                   float* __restrict__ out) {
    __shared__ float    lds[16384];    // 64 KB = 256 pixels x 64 C
    __shared__ unsigned rstart[TPB];   // run start (global record idx)
    __shared__ unsigned short rlen[TPB];

    const int t = threadIdx.x;
    const int bucket = blockIdx.x;
    const int batch  = bucket >> 10;
    const int b      = bucket & 1023;

    // issue run-bound loads FIRST (scattered u16 pairs; latency overlaps zeroing)
    if (t < TPB) {
        int tile = (batch << 8) + t;
        unsigned s = pfx_tab[tile * BPB + b];
        unsigned e = (b == BPB - 1) ? (unsigned)TILE : pfx_tab[tile * BPB + b + 1];
        rstart[t] = (unsigned)tile * TILE + s;
        rlen[t]   = (unsigned short)(e - s);
    }

    f4v* lds4 = reinterpret_cast<f4v*>(lds);
    f4v z = {0.f, 0.f, 0.f, 0.f};
    #pragma unroll
    for (int k = 0; k < 4; ++k)
        lds4[t + BS * k] = z;
    __syncthreads();

    // drain: run = t>>2, portion = t&3. ~4 records each, independent iters.
    {
        const unsigned run = (unsigned)t >> 2;
        const unsigned p   = (unsigned)t & 3u;
        const unsigned len = rlen[run];
        const unsigned q0  = (len * p) >> 2;
        const unsigned q1  = (len * (p + 1u)) >> 2;
        const unsigned* r = rec + rstart[run];
        for (unsigned i = q0; i < q1; ++i) {
            unsigned e = r[i];
            atomicAdd(&lds[e & 16383u], __uint_as_float(e & 0xFFFFC000u));
        }
    }
    __syncthreads();

    // dense output write: NONTEMPORAL stores — keep the 512 MB stream out of
    // L2/L3 so the record array stays cache-resident for later gather WGs.
    size_t obase = ((size_t)batch << 24) + ((size_t)b << 14);
    f4v* out4 = reinterpret_cast<f4v*>(out + obase);
    #pragma unroll
    for (int k = 0; k < 4; ++k)
        __builtin_nontemporal_store(lds4[t + BS * k], &out4[t + BS * k]);
}

// ---- Fallback: direct atomic scatter (round-1) ----------------------------
__global__ void unpool_scatter(const float* __restrict__ upd,
                               const int*  __restrict__ mask,
                               float*      __restrict__ out) {
    int i = blockIdx.x * blockDim.x + threadIdx.x;
    int base = i << 2;
    if (base >= N_ELEM) return;
    const int4   m = reinterpret_cast<const int4*>(mask)[i];
    const float4 u = reinterpret_cast<const float4*>(upd)[i];
    int b = base >> 22;
    int c = base & 63;
    size_t obase = ((size_t)b << 24) + c;
    atomicAdd(&out[obase + (size_t)(m.x & ~63)    ], u.x);
    atomicAdd(&out[obase + (size_t)(m.y & ~63) + 1], u.y);
    atomicAdd(&out[obase + (size_t)(m.z & ~63) + 2], u.z);
    atomicAdd(&out[obase + (size_t)(m.w & ~63) + 3], u.w);
}

extern "C" void kernel_launch(void* const* d_in, const int* in_sizes, int n_in,
                              void* d_out, int out_size, void* d_ws, size_t ws_size,
                              hipStream_t stream) {
    const float* upd  = (const float*)d_in[0];
    const int*   mask = (const int*)d_in[1];
    float*       out  = (float*)d_out;

    if (ws_size < PFX_BYTES + REC_BYTES) {
        hipMemsetAsync(out, 0, (size_t)out_size * sizeof(float), stream);
        int n4 = N_ELEM / 4;
        unpool_scatter<<<(n4 + 255) / 256, 256, 0, stream>>>(upd, mask, out);
        return;
    }

    unsigned short* pfx_tab = (unsigned short*)d_ws;
    unsigned*       rec     = (unsigned*)((char*)d_ws + PFX_BYTES);

    bin16k<<<NTILE, BS, SREC_BYTES, stream>>>(upd, mask, pfx_tab, rec);
    bucket_gather<<<NBUCK, BS, 0, stream>>>(rec, pfx_tab, out);
}